// Round 9
// baseline (707.024 us; speedup 1.0000x reference)
//
#include <hip/hip_runtime.h>
#include <math.h>

// Problem constants
#define BB 512
#define RR 640
#define CC 10
#define OO 16
#define CO 160   // C*O
#define II 8

#define ZCH (RR*CO)           // zero 16B-chunk index in wf (appended by prep)
#define LSTR 165              // LDS co-stride for red (breaks pow-2 banks)
#define VSTR 164              // LDS co-stride for v tile (2-way max = free)

// Fused config: ONE block per b-tile (32 blocks x 1024 threads = 16 waves).
// Each wave owns 40 r's (16 x 40 = 640). All 3 routing iterations run
// in-block: the only sync mechanism is __syncthreads(). No cross-block
// communication of any kind (R4: atomics sound but ~50us; R5: store+flag
// unsound; R6/R8: dispatch-boundary version has a ~90us 7-dispatch floor).
#define WVF 16                // waves per block
#define RPWF 40               // r per wave

#define XF_CHUNKS (RR*BB)         // 327680 f16x8 chunks
#define WF_CHUNKS (RR*CO*II/8)    // 102400 f16x8 chunks
#define PREP_BLOCKS ((XF_CHUNKS + WF_CHUNKS)/256 + 1)   // 1681

using f16x8 = __attribute__((ext_vector_type(8))) _Float16;  // 8 f16 (4 VGPRs)
using f32x4 = __attribute__((ext_vector_type(4))) float;     // 4 fp32

// Identity: routing logits at iter k equal u_hat . (v_0+...+v_{k-1}),
// so we carry only the accumulated v in LDS (vlds), updated by wave 0.

// ---------- helpers ----------

// exp(a) for |a| < ~0.15 (routing logits are u.v ~ O(1e-2)):
// 3rd-order Taylor, error a^4/24 < 2e-5 — far below the 2.4e-3 threshold.
__device__ __forceinline__ float exp_small(float a) {
    float f = __builtin_fmaf(a, 0.16666667f, 0.5f);
    f = __builtin_fmaf(a, f, 1.0f);
    return __builtin_fmaf(a, f, 1.0f);
}

__device__ __forceinline__ f16x8 cvt8(const float4 lo, const float4 hi) {
    f16x8 v;
    v[0] = (_Float16)lo.x; v[1] = (_Float16)lo.y;
    v[2] = (_Float16)lo.z; v[3] = (_Float16)lo.w;
    v[4] = (_Float16)hi.x; v[5] = (_Float16)hi.y;
    v[6] = (_Float16)hi.z; v[7] = (_Float16)hi.w;
    return v;
}

// ---------- prep: W->f16 (+zero slot), x->f16 transposed ----------
// Vectorized (R6/R8 harness-verified): one f16x8 chunk per thread.
//   xf chunk t = r*BB + b holds x[b][r][0..8)   (b = t&511, r = t>>9)
//   wf chunk u holds W[8u .. 8u+8) linear

__global__ __launch_bounds__(256) void prep(const float* __restrict__ W,
                                            const float* __restrict__ x,
                                            _Float16* __restrict__ wf,
                                            _Float16* __restrict__ xf) {
    const int t = blockIdx.x * 256 + threadIdx.x;
    if (t < XF_CHUNKS) {
        const int b = t & (BB - 1);
        const int r = t >> 9;
        const float4* xp = reinterpret_cast<const float4*>(x) + (size_t)(b * RR + r) * 2;
        const float4 lo = xp[0];
        const float4 hi = xp[1];
        reinterpret_cast<f16x8*>(xf)[t] = cvt8(lo, hi);
    } else if (t < XF_CHUNKS + WF_CHUNKS) {
        const int u = t - XF_CHUNKS;
        const float4* wp = reinterpret_cast<const float4*>(W) + (size_t)u * 2;
        const float4 lo = wp[0];
        const float4 hi = wp[1];
        reinterpret_cast<f16x8*>(wf)[u] = cvt8(lo, hi);
    } else {
        const int u = t - (XF_CHUNKS + WF_CHUNKS);   // 0..255 (last block)
        if (u < 16) wf[RR * CO * II + u] = (_Float16)0.f;  // zero chunk (A padding)
    }
}

// ---------- pass (device): one wave, 40 r's ----------
// Wave layout: n = lane&15 (b within tile; also A's m row), q = lane>>4.
// Routing math byte-identical to the harness-verified R8 path.
// UNIFORM: quads K-pack 4 consecutive r's (40 = 10 full chunks, REM=0).
// else: per-r u-MFMA on quad 0 (others ZCH), softmax over c, weighted accum.

template <bool UNIFORM>
__device__ __forceinline__ void run_pass(const _Float16* __restrict__ wf,
                                         const _Float16* __restrict__ xf,
                                         const float* __restrict__ vlds,
                                         f32x4 (&sacc)[CC],
                                         int b0, int r0, int n, int q) {
    const bool q0 = (q == 0);
    const f16x8* xq = reinterpret_cast<const f16x8*>(xf);  // chunk = r*BB + b
    const int4*  wq = reinterpret_cast<const int4*>(wf);   // chunk = r*CO + co

#pragma unroll
    for (int c = 0; c < CC; ++c) sacc[c] = (f32x4){0.f, 0.f, 0.f, 0.f};

    if (UNIFORM) {
#pragma unroll 2
        for (int rr = 0; rr + 4 <= RPWF; rr += 4) {  // 10 full 4-r K-packed chunks
            const int r = r0 + rr + q;
            const f16x8 bfr = xq[(size_t)r * BB + b0 + n];
#pragma unroll
            for (int c = 0; c < CC; ++c) {
                const int4 a = wq[r * CO + c * 16 + n];
                sacc[c] = __builtin_amdgcn_mfma_f32_16x16x32_f16(
                    __builtin_bit_cast(f16x8, a), bfr, sacc[c], 0, 0, 0);
            }
        }
    } else {
        f32x4 vv[CC];
        const float* vp = vlds + n * VSTR;
#pragma unroll
        for (int c = 0; c < CC; ++c)
            vv[c] = *reinterpret_cast<const f32x4*>(vp + c * 16 + 4 * q);

#pragma unroll 2
        for (int rr = 0; rr < RPWF; ++rr) {
            const int r = r0 + rr;
            const f16x8 bcur = xq[(size_t)r * BB + b0 + n];

            f32x4 acc[CC];
#pragma unroll
            for (int c = 0; c < CC; ++c) {
                const int4 a = wq[q0 ? (r * CO + c * 16 + n) : ZCH];
                acc[c] = __builtin_amdgcn_mfma_f32_16x16x32_f16(
                    __builtin_bit_cast(f16x8, a), bcur,
                    (f32x4){0.f, 0.f, 0.f, 0.f}, 0, 0, 0);
            }

            float e[CC];
#pragma unroll
            for (int c = 0; c < CC; ++c) {
                float t = acc[c][0] * vv[c][0] + acc[c][1] * vv[c][1]
                        + acc[c][2] * vv[c][2] + acc[c][3] * vv[c][3];
                t += __shfl_xor(t, 16);
                t += __shfl_xor(t, 32);     // full sum over o (4 quads x 4 regs)
                e[c] = exp_small(t);
            }
            const float se = (((e[0] + e[1]) + (e[2] + e[3]))
                            + ((e[4] + e[5]) + (e[6] + e[7]))) + (e[8] + e[9]);
            const float inv = __fdividef(1.0f, se);
#pragma unroll
            for (int c = 0; c < CC; ++c) {
                const float w = e[c] * inv;
#pragma unroll
                for (int k = 0; k < 4; ++k)
                    sacc[c][k] = __builtin_fmaf(w, acc[c][k], sacc[c][k]);
            }
        }
    }
}

// ---------- in-block reduce (16 waves -> 4 LDS slots -> wave 0) + squash ----------
// mode 0: vlds = v   mode 1: vlds += v   mode 2: out = v
// f: 0.1 for the uniform pass (softmax(0) over C=10), else 1.

__device__ __forceinline__ void reduce_squash(const f32x4 (&sacc)[CC],
                                              float* __restrict__ red,
                                              float* __restrict__ vlds,
                                              const float* __restrict__ bias,
                                              float* __restrict__ out,
                                              int mode, float f,
                                              int wv, int n, int q, int b0) {
    const int cb = 4 * q;
    // 4-slot tree: waves 0-3 write, then three add-rounds
    if (wv < 4) {
        float* d = red + ((wv * 16 + n) * LSTR + cb);
#pragma unroll
        for (int c = 0; c < CC; ++c)
#pragma unroll
            for (int k = 0; k < 4; ++k) d[c * 16 + k] = sacc[c][k];
    }
    __syncthreads();
    if (wv >= 4 && wv < 8) {
        float* d = red + (((wv - 4) * 16 + n) * LSTR + cb);
#pragma unroll
        for (int c = 0; c < CC; ++c)
#pragma unroll
            for (int k = 0; k < 4; ++k) d[c * 16 + k] += sacc[c][k];
    }
    __syncthreads();
    if (wv >= 8 && wv < 12) {
        float* d = red + (((wv - 8) * 16 + n) * LSTR + cb);
#pragma unroll
        for (int c = 0; c < CC; ++c)
#pragma unroll
            for (int k = 0; k < 4; ++k) d[c * 16 + k] += sacc[c][k];
    }
    __syncthreads();
    if (wv >= 12) {
        float* d = red + (((wv - 12) * 16 + n) * LSTR + cb);
#pragma unroll
        for (int c = 0; c < CC; ++c)
#pragma unroll
            for (int k = 0; k < 4; ++k) d[c * 16 + k] += sacc[c][k];
    }
    __syncthreads();
    if (wv == 0) {
        const float* s0 = red + ((0 * 16 + n) * LSTR + cb);
        const float* s1 = red + ((1 * 16 + n) * LSTR + cb);
        const float* s2 = red + ((2 * 16 + n) * LSTR + cb);
        const float* s3 = red + ((3 * 16 + n) * LSTR + cb);
#pragma unroll
        for (int c = 0; c < CC; ++c) {
            f32x4 sv;
#pragma unroll
            for (int k = 0; k < 4; ++k)
                sv[k] = __builtin_fmaf(((s0[c * 16 + k] + s1[c * 16 + k])
                                      + (s2[c * 16 + k] + s3[c * 16 + k])), f,
                                       bias[c * 16 + cb + k]);
            // squash: sq over all 16 o (4 regs here + 2 shfl across quads)
            float t = sv[0] * sv[0] + sv[1] * sv[1] + sv[2] * sv[2] + sv[3] * sv[3];
            t += __shfl_xor(t, 16);
            t += __shfl_xor(t, 32);
            const float norm  = sqrtf(t);
            const float scale = norm / (1.0f + t + 1e-8f);
            f32x4 v;
#pragma unroll
            for (int k = 0; k < 4; ++k) v[k] = scale * sv[k];
            if (mode == 2) {
                *reinterpret_cast<f32x4*>(out + (size_t)(b0 + n) * CO + c * 16 + cb) = v;
            } else {
                f32x4* vl = reinterpret_cast<f32x4*>(vlds + n * VSTR + c * 16 + cb);
                if (mode == 1) v += vl[0];
                vl[0] = v;
            }
        }
    }
    __syncthreads();    // vlds (and red reuse) visible to all waves
}

// ---------- fused kernel: one block per b-tile, all 3 iterations ----------

__global__ __launch_bounds__(1024, 1) void caps_all(const _Float16* __restrict__ wf,
                                                    const _Float16* __restrict__ xf,
                                                    const float* __restrict__ bias,
                                                    float* __restrict__ out) {
    __shared__ __align__(16) float red[4 * 16 * LSTR];   // 42.2 KB
    __shared__ __align__(16) float vlds[16 * VSTR];      // 10.5 KB
    const int tid  = threadIdx.x;
    const int lane = tid & 63;
    const int wv   = tid >> 6;            // 0..15
    const int n    = lane & 15;
    const int q    = lane >> 4;
    const int bt   = blockIdx.x;          // 0..31
    const int b0   = bt * 16;
    const int r0   = wv * RPWF;           // 16 waves x 40 r = 640

    f32x4 sacc[CC];

    // iter 0: uniform weights -> v0
    run_pass<true>(wf, xf, nullptr, sacc, b0, r0, n, q);
    reduce_squash(sacc, red, vlds, bias, nullptr, 0, 0.1f, wv, n, q, b0);

    // iter 1: logits = u.v0 -> vlds = v0 + v1
    run_pass<false>(wf, xf, vlds, sacc, b0, r0, n, q);
    reduce_squash(sacc, red, vlds, bias, nullptr, 1, 1.0f, wv, n, q, b0);

    // iter 2: logits = u.(v0+v1) -> out
    run_pass<false>(wf, xf, vlds, sacc, b0, r0, n, q);
    reduce_squash(sacc, red, vlds, bias, out, 2, 1.0f, wv, n, q, b0);
}

// ---------- launch ----------

extern "C" void kernel_launch(void* const* d_in, const int* in_sizes, int n_in,
                              void* d_out, int out_size, void* d_ws, size_t ws_size,
                              hipStream_t stream) {
    const float* x    = (const float*)d_in[0];   // [512,640,8]
    const float* W    = (const float*)d_in[1];   // [640,10,16,8]
    const float* bias = (const float*)d_in[2];   // [1,1,10,16]
    float* out  = (float*)d_out;                 // [512,10,16]

    // Workspace (~6.9 MiB): only the f16 staging buffers.
    _Float16* wf = (_Float16*)d_ws;                      // 1.64 MB (+zero chunk)
    _Float16* xf = wf + (size_t)RR * CO * II + 16;       // 5.24 MB (+16: 16B align)

    prep    <<<PREP_BLOCKS, 256, 0, stream>>>(W, x, wf, xf);
    caps_all<<<dim3(32), 1024, 0, stream>>>(wf, xf, bias, out);
}